// Round 10
// baseline (114.989 us; speedup 1.0000x reference)
//
#include <hip/hip_runtime.h>
#include <math.h>

#define B_   4
#define L_   1024
#define H_   768
#define NH_  12
#define E_   24
#define M_   4
#define P_   552
#define NL_  97
#define H2_  1536          // 2*H
#define HB_  49152         // H*BLK
#define R_   2208          // B*P
#define NEG_ (-1e30f)

// logits MFMA tiling: BM=256 (4 waves x ms=4), 9 r-tiles, 48 K-chunks of 1024
#define RT2_  9
#define PR2_  2304         // RT2*256
#define S_    48
#define NTIL_ 7            // 112 padded cols / 16
#define KT_   1536         // HB/32 k-steps total

typedef _Float16 h2   __attribute__((ext_vector_type(2)));
typedef _Float16 f16x8 __attribute__((ext_vector_type(8)));
typedef float    f32x4 __attribute__((ext_vector_type(4)));

__device__ inline uint pkh(float lo, float hi) {      // fast RTZ pack
    union { __fp16 v __attribute__((ext_vector_type(2))); uint u; } c;
    c.v = __builtin_amdgcn_cvt_pkrtz(lo, hi);
    return c.u;
}
__device__ inline ushort h_rne(float x) {
    union { _Float16 h; ushort u; } c; c.h = (_Float16)x; return c.u;
}
__device__ inline uint h2_rne(float lo, float hi) {
    return (uint)h_rne(lo) | ((uint)h_rne(hi) << 16);
}

// ---------------- fused pack + ent_att + ent_emb ---------------------------
// ATT [0,1152) | WB-tiles [1152,1824) | W-tiles [1824,2112) |
// SEQ [2112,3648) | EMB [3648,3744)
#define PKB_ATT 1152
#define PKB_WB2 672      // 7 nt x 96 kb (512-k tiles)
#define PKB_W2  288      // 2 x (48 nt x 3 kb)
#define PKB_SEQ 1536
#define PKB_EMB 96
#define LDSTR   516      // floats per staged row (16B aligned, stride%32==4)

__global__ void k_pack(const float* __restrict__ att, const float* __restrict__ Wb,
                       const float* __restrict__ Wh, const float* __restrict__ Wt,
                       const float* __restrict__ seq,
                       const int* __restrict__ midx, const float* __restrict__ mmask,
                       _Float16* __restrict__ ea, _Float16* __restrict__ WbP,
                       _Float16* __restrict__ WhP, _Float16* __restrict__ WtP,
                       _Float16* __restrict__ seqP, _Float16* __restrict__ ee) {
    __shared__ float lds[16][LDSTR];    // 33 KB, used by WB/W segments only
    int bid = blockIdx.x;
    if (bid < PKB_ATT) {                    // entity_atts -> fp16 (float4 loads)
        int blk = bid;                      // (b*E+e)*NH + n
        int n  = blk % NH_;
        int be = blk / NH_;
        int b  = be / E_;
        int idx[M_]; float msk[M_]; float denom = 0.f;
#pragma unroll
        for (int m = 0; m < M_; ++m) { idx[m] = midx[be*M_+m]; msk[m] = mmask[be*M_+m]; denom += msk[m]; }
        float inv = 1.f / denom;
        const float* abase = att + (size_t)(b*NH_ + n) * L_ * L_;
        int l4 = threadIdx.x * 4;           // 256 threads x 4 = 1024
        float s0 = 0.f, s1 = 0.f, s2 = 0.f, s3 = 0.f;
#pragma unroll
        for (int m = 0; m < M_; ++m) {
            float4 a = *(const float4*)(abase + idx[m]*L_ + l4);
            s0 += msk[m]*a.x; s1 += msk[m]*a.y; s2 += msk[m]*a.z; s3 += msk[m]*a.w;
        }
        *(uint2*)(ea + (((size_t)(be*NH_ + n)) << 10) + l4) =
            make_uint2(pkh(s0*inv, s1*inv), pkh(s2*inv, s3*inv));
        return;
    }
    if (bid < PKB_ATT + PKB_WB2 + PKB_W2) { // weight tiles via LDS transpose
        int seg = bid - PKB_ATT;
        const float* W; _Float16* WP; int nt, kb, N16, Nvalid, Kdim;
        if (seg < PKB_WB2) {                // Wb: N16=7, K=49152
            W = Wb; WP = WbP; N16 = 7; Nvalid = NL_; Kdim = HB_;
            nt = seg % 7; kb = seg / 7;     // kb 0..95
        } else {                            // Wh/Wt: N16=48, K=1536
            int s2 = seg - PKB_WB2;
            int which = s2 / 144;
            int s = s2 % 144;
            W = which ? Wt : Wh; WP = which ? WtP : WhP;
            N16 = 48; Nvalid = H_; Kdim = H2_;
            nt = s % 48; kb = s / 48;       // kb 0..2
        }
        int k0 = kb * 512;
        // stage 16 rows x 512 cols, fully coalesced float4
#pragma unroll
        for (int it = 0; it < 8; ++it) {
            int f4 = threadIdx.x + it*256;  // 0..2047
            int row = f4 >> 7;              // 16 rows
            int c4  = (f4 & 127) << 2;      // 512 cols
            int n   = nt*16 + row;
            float4 v = make_float4(0.f,0.f,0.f,0.f);
            if (n < Nvalid) v = *(const float4*)(W + (size_t)n*Kdim + k0 + c4);
            *(float4*)&lds[row][c4] = v;
        }
        __syncthreads();
        int kt0 = kb * 16;
#pragma unroll
        for (int it = 0; it < 4; ++it) {
            int fi = threadIdx.x + it*256;  // 0..1023
            int kt_l = fi >> 6, lane = fi & 63;
            int n_l = lane & 15;
            int k_l = kt_l*32 + ((lane >> 4) << 3);
            float4 a = *(const float4*)&lds[n_l][k_l];
            float4 b = *(const float4*)&lds[n_l][k_l + 4];
            uint4 w = make_uint4(h2_rne(a.x,a.y), h2_rne(a.z,a.w),
                                 h2_rne(b.x,b.y), h2_rne(b.z,b.w));
            *(uint4*)(WP + (((size_t)(kt0 + kt_l)*N16 + nt) << 9) + lane*8) = w;
        }
        return;
    }
    if (bid < PKB_ATT + PKB_WB2 + PKB_W2 + PKB_SEQ) {   // seq -> per-b frag
        int t = (bid - PKB_ATT - PKB_WB2 - PKB_W2)*256 + threadIdx.x;
        int lane = t & 63;
        int rest = t >> 6;
        int nt = rest % 48; rest /= 48;
        int kt = rest % 32;
        int b  = rest / 32;
        int n = nt*16 + (lane & 15);
        int k = kt*32 + ((lane >> 4) << 3);
        const float* src = seq + ((size_t)(b*L_ + k))*H_ + n;
        uint w[4];
#pragma unroll
        for (int e = 0; e < 4; ++e) w[e] = h2_rne(src[(2*e)*H_], src[(2*e+1)*H_]);
        *(uint4*)(seqP + (size_t)t*8) = make_uint4(w[0],w[1],w[2],w[3]);
        return;
    }
    // ent_emb: logsumexp over mentions -> fp16
    int be = bid - (PKB_ATT + PKB_WB2 + PKB_W2 + PKB_SEQ);
    int b  = be / E_;
    int idx[M_]; float msk[M_];
#pragma unroll
    for (int m = 0; m < M_; ++m) { idx[m] = midx[be*M_+m]; msk[m] = mmask[be*M_+m]; }
    for (int d = threadIdx.x; d < H_; d += 256) {
        float v[M_]; float mx = NEG_;
#pragma unroll
        for (int m = 0; m < M_; ++m) {
            v[m] = (msk[m] > 0.f) ? seq[(b*L_ + idx[m])*H_ + d] : NEG_;
            mx = fmaxf(mx, v[m]);
        }
        float s = 0.f;
#pragma unroll
        for (int m = 0; m < M_; ++m) s += expf(v[m] - mx);
        ee[be*H_ + d] = (_Float16)(mx + logf(s));
    }
}

// ---------------- K3: ht_att (128 threads, 16B loads) ----------------------
__global__ void k_ht_att(const _Float16* __restrict__ ea, const int* __restrict__ hts,
                         _Float16* __restrict__ ht) {
    __shared__ float red[2];
    int bp = blockIdx.x;            // b*P+p
    int b  = bp / P_;
    int h = hts[bp*2+0], t = hts[bp*2+1];
    const uint4* eh4 = (const uint4*)(ea + ((size_t)(b*E_ + h)*NH_ << 10));
    const uint4* et4 = (const uint4*)(ea + ((size_t)(b*E_ + t)*NH_ << 10));
    int lp = threadIdx.x;           // 0..127, each covers l = lp*8..+7
    float s[8] = {};
#pragma unroll
    for (int n = 0; n < NH_; ++n) {
        union { uint4 u; h2 v[4]; } A, C;
        A.u = eh4[n*128 + lp];
        C.u = et4[n*128 + lp];
#pragma unroll
        for (int q = 0; q < 4; ++q) {
            s[2*q]   += (float)A.v[q][0]*(float)C.v[q][0];
            s[2*q+1] += (float)A.v[q][1]*(float)C.v[q][1];
        }
    }
    float local = 0.f;
#pragma unroll
    for (int q = 0; q < 8; ++q) { s[q] *= (1.f/NH_); local += s[q]; }
#pragma unroll
    for (int o = 32; o > 0; o >>= 1) local += __shfl_down(local, o);
    int wid = threadIdx.x >> 6, lane = threadIdx.x & 63;
    if (lane == 0) red[wid] = local;
    __syncthreads();
    if (threadIdx.x == 0) red[0] = 1.f / (red[0] + red[1] + 1e-5f);
    __syncthreads();
    float inv = red[0];
    *(uint4*)(ht + ((size_t)bp << 10) + lp*8) =
        make_uint4(pkh(s[0]*inv, s[1]*inv), pkh(s[2]*inv, s[3]*inv),
                   pkh(s[4]*inv, s[5]*inv), pkh(s[6]*inv, s[7]*inv));
}

// ---------------- K4: rs = ht @ seq, BM=128 (ms=2), XCD-pinned b -----------
__launch_bounds__(256, 4)
__global__ void k_rs_mfma(const _Float16* __restrict__ ht, const _Float16* __restrict__ seqP,
                          _Float16* __restrict__ rs) {
    __shared__ _Float16 as[128*72];
    int bid = blockIdx.x;
    int xcd = bid & 7, jj0 = bid >> 3;   // jj0 0..29
    int b    = xcd >> 1;
    int tile = (xcd & 1)*30 + jj0;       // 0..59
    int p0   = (tile % 5) * 128;
    int nt0  = (tile / 5) * 4;
    int wave = threadIdx.x >> 6, lane = threadIdx.x & 63;

    const _Float16* srcp[4];
    int ldst[4];
#pragma unroll
    for (int i = 0; i < 4; ++i) {
        int t = threadIdx.x + i*256;
        int row = t >> 3, c8 = (t & 7)*8;
        int p = p0 + row;
        srcp[i] = (p < P_) ? ht + (((size_t)(b*P_ + p)) << 10) + c8 : nullptr;
        ldst[i] = row*72 + c8;
    }
    uint4 st[4];
#pragma unroll
    for (int i = 0; i < 4; ++i)
        st[i] = srcp[i] ? *(const uint4*)(srcp[i]) : make_uint4(0,0,0,0);

    f32x4 acc[2][4] = {};
    const _Float16* wbase = seqP + ((size_t)b*32*48 + nt0)*512 + lane*8;
    int rowbase = wave*32 + (lane & 15);
    int asub = (lane >> 4) << 3;

    for (int kc = 0; kc < 16; ++kc) {
        if (kc) __syncthreads();
#pragma unroll
        for (int i = 0; i < 4; ++i) *(uint4*)(as + ldst[i]) = st[i];
        __syncthreads();
        if (kc + 1 < 16) {
#pragma unroll
            for (int i = 0; i < 4; ++i)
                st[i] = srcp[i] ? *(const uint4*)(srcp[i] + (kc+1)*64) : make_uint4(0,0,0,0);
        }
#pragma unroll
        for (int kk = 0; kk < 2; ++kk) {
            int kt = kc*2 + kk;
            const _Float16* wp = wbase + (size_t)kt*(48*512);
            f16x8 bf[4];
#pragma unroll
            for (int jn = 0; jn < 4; ++jn) bf[jn] = *(const f16x8*)(wp + jn*512);
#pragma unroll
            for (int ms = 0; ms < 2; ++ms) {
                f16x8 af = *(const f16x8*)(as + (rowbase + ms*16)*72 + kk*32 + asub);
#pragma unroll
                for (int jn = 0; jn < 4; ++jn)
                    acc[ms][jn] = __builtin_amdgcn_mfma_f32_16x16x32_f16(af, bf[jn], acc[ms][jn], 0, 0, 0);
            }
        }
    }
    int crow = (lane >> 4) * 4;
    int ccol = lane & 15;
#pragma unroll
    for (int ms = 0; ms < 2; ++ms) {
#pragma unroll
        for (int jn = 0; jn < 4; ++jn) {
            int n = nt0*16 + jn*16 + ccol;
#pragma unroll
            for (int reg = 0; reg < 4; ++reg) {
                int p = p0 + wave*32 + ms*16 + crow + reg;
                if (p < P_) rs[(size_t)(b*P_ + p)*H_ + n] = (_Float16)acc[ms][jn][reg];
            }
        }
    }
}

// ---------------- K5: zh & zt, BM=128 (ms=2), XCD-pinned which -------------
__launch_bounds__(256, 4)
__global__ void k_z_mfma(const _Float16* __restrict__ ee, const _Float16* __restrict__ rs,
                         const _Float16* __restrict__ WhP, const _Float16* __restrict__ WtP,
                         const float* __restrict__ bh, const float* __restrict__ bt,
                         const int* __restrict__ hts,
                         _Float16* __restrict__ zh, _Float16* __restrict__ zt) {
    __shared__ _Float16 as[128*72];
    int bid = blockIdx.x;
    int xcd = bid & 7, jj0 = bid >> 3;   // jj0 0..53
    int which = xcd >> 2;
    int tile  = (xcd & 3)*54 + jj0;      // 0..215
    int r0  = (tile % 18) * 128;
    int nt0 = (tile / 18) * 4;
    const _Float16* WP   = which ? WtP : WhP;
    const float*    bias = which ? bt  : bh;
    _Float16*       out  = which ? zt  : zh;
    int wave = threadIdx.x >> 6, lane = threadIdx.x & 63;

    const _Float16* srcA[4];
    const _Float16* srcB[4];
    int ldst[4];
#pragma unroll
    for (int i = 0; i < 4; ++i) {
        int t = threadIdx.x + i*256;
        int row = t >> 3, c8 = (t & 7)*8;
        int r = r0 + row;
        if (r < R_) {
            int b = r / P_;
            int eidx = hts[r*2 + which];
            srcA[i] = ee + (size_t)(b*E_ + eidx)*H_ + c8;
            srcB[i] = rs + (size_t)r*H_ + c8;
        } else { srcA[i] = nullptr; srcB[i] = nullptr; }
        ldst[i] = row*72 + c8;
    }
    uint4 st[4];
#pragma unroll
    for (int i = 0; i < 4; ++i)
        st[i] = srcA[i] ? *(const uint4*)(srcA[i]) : make_uint4(0,0,0,0);

    f32x4 acc[2][4] = {};
    const _Float16* wbase = WP + (size_t)nt0*512 + lane*8;
    int rowbase = wave*32 + (lane & 15);
    int asub = (lane >> 4) << 3;

    for (int kc = 0; kc < 24; ++kc) {
        if (kc) __syncthreads();
#pragma unroll
        for (int i = 0; i < 4; ++i) *(uint4*)(as + ldst[i]) = st[i];
        __syncthreads();
        if (kc + 1 < 24) {
            int kn = kc + 1;
#pragma unroll
            for (int i = 0; i < 4; ++i) {
                const _Float16* s = (kn < 12) ? (srcA[i] ? srcA[i] + kn*64 : nullptr)
                                              : (srcB[i] ? srcB[i] + (kn-12)*64 : nullptr);
                st[i] = s ? *(const uint4*)s : make_uint4(0,0,0,0);
            }
        }
#pragma unroll
        for (int kk = 0; kk < 2; ++kk) {
            int kt = kc*2 + kk;
            const _Float16* wp = wbase + (size_t)kt*(48*512);
            f16x8 bf[4];
#pragma unroll
            for (int jn = 0; jn < 4; ++jn) bf[jn] = *(const f16x8*)(wp + jn*512);
#pragma unroll
            for (int ms = 0; ms < 2; ++ms) {
                f16x8 af = *(const f16x8*)(as + (rowbase + ms*16)*72 + kk*32 + asub);
#pragma unroll
                for (int jn = 0; jn < 4; ++jn)
                    acc[ms][jn] = __builtin_amdgcn_mfma_f32_16x16x32_f16(af, bf[jn], acc[ms][jn], 0, 0, 0);
            }
        }
    }
    int crow = (lane >> 4) * 4;
    int ccol = lane & 15;
#pragma unroll
    for (int ms = 0; ms < 2; ++ms) {
#pragma unroll
        for (int jn = 0; jn < 4; ++jn) {
            int n = nt0*16 + jn*16 + ccol;
            float bv = bias[n];
#pragma unroll
            for (int reg = 0; reg < 4; ++reg) {
                int r = r0 + wave*32 + ms*16 + crow + reg;
                if (r < R_) out[(size_t)r*H_ + n] = (_Float16)tanhf(acc[ms][jn][reg] + bv);
            }
        }
    }
}

// ---------------- K6: logits — BM=256, 4 waves, ms=4, S=48, fp16 part ------
__launch_bounds__(256, 2)
__global__ void k_logits_mfma(const _Float16* __restrict__ zh, const _Float16* __restrict__ zt,
                              const _Float16* __restrict__ WbP, _Float16* __restrict__ part) {
    __shared__ _Float16 zhs[256*20];   // 10 KB
    __shared__ _Float16 zts[256*72];   // 36.9 KB
    int bid = blockIdx.x;
    int xcd = bid & 7, j = bid >> 3;   // j 0..53
    int kc  = xcd*6 + j/9;             // 0..47
    int rt  = j % 9;
    int r0  = rt * 256;
    int g64 = (kc >> 2) * 64;          // zt col base
    int a0  = (kc & 3) * 16;           // zh col base within g

    for (int it = 0; it < 2; ++it) {
        int t = threadIdx.x + it*256;
        int row = t >> 1, i8 = (t & 1)*8;
        int r = r0 + row;
        uint4 w = make_uint4(0,0,0,0);
        if (r < R_) w = *(const uint4*)(zh + (size_t)r*H_ + g64 + a0 + i8);
        *(uint4*)(zhs + row*20 + i8) = w;
    }
    for (int it = 0; it < 8; ++it) {
        int t = threadIdx.x + it*256;
        int row = t >> 3, j8 = (t & 7)*8;
        int r = r0 + row;
        uint4 w = make_uint4(0,0,0,0);
        if (r < R_) w = *(const uint4*)(zt + (size_t)r*H_ + g64 + j8);
        *(uint4*)(zts + row*72 + j8) = w;
    }
    __syncthreads();

    int wave = threadIdx.x >> 6, lane = threadIdx.x & 63;
    int rowA0 = wave*64 + (lane & 15);    // wave covers 64 rows (ms=4)
    int jsub  = (lane >> 4) * 8;

    f32x4 acc[4][NTIL_] = {};
    const _Float16* wb0 = WbP + (size_t)(kc*32) * (NTIL_*512) + lane*8;

    f16x8 bf[NTIL_];
#pragma unroll
    for (int nt = 0; nt < NTIL_; ++nt) bf[nt] = *(const f16x8*)(wb0 + nt*512);

    for (int ktl = 0; ktl < 32; ++ktl) {
        f16x8 bn[NTIL_];
        if (ktl + 1 < 32) {
            const _Float16* wp = wb0 + (size_t)(ktl+1) * (NTIL_*512);
#pragma unroll
            for (int nt = 0; nt < NTIL_; ++nt) bn[nt] = *(const f16x8*)(wp + nt*512);
        }
        int il = ktl >> 1;
        int jb = (ktl & 1) * 32 + jsub;
#pragma unroll
        for (int ms = 0; ms < 4; ++ms) {
            int row = rowA0 + ms*16;
            _Float16 hv = zhs[row*20 + il];
            h2 hb = {hv, hv};
            union { uint4 u; h2 v[4]; } T;
            T.u = *(const uint4*)(zts + row*72 + jb);
            union { h2 v[4]; f16x8 f; } A;
            A.v[0] = hb * T.v[0];
            A.v[1] = hb * T.v[1];
            A.v[2] = hb * T.v[2];
            A.v[3] = hb * T.v[3];
#pragma unroll
            for (int nt = 0; nt < NTIL_; ++nt)
                acc[ms][nt] = __builtin_amdgcn_mfma_f32_16x16x32_f16(A.f, bf[nt], acc[ms][nt], 0, 0, 0);
        }
        if (ktl + 1 < 32) {
#pragma unroll
            for (int nt = 0; nt < NTIL_; ++nt) bf[nt] = bn[nt];
        }
    }

    int crow0 = wave*64 + (lane >> 4) * 4;
    int ccol  = lane & 15;
#pragma unroll
    for (int ms = 0; ms < 4; ++ms) {
#pragma unroll
        for (int nt = 0; nt < NTIL_; ++nt) {
#pragma unroll
            for (int reg = 0; reg < 4; ++reg) {
                int rp = r0 + crow0 + ms*16 + reg;
                part[((size_t)kc*PR2_ + rp)*112 + nt*16 + ccol] = (_Float16)acc[ms][nt][reg];
            }
        }
    }
}

// ---------------- K7: reduce fp16 partials + bias --------------------------
__global__ void k_logits_reduce(const _Float16* __restrict__ part, const float* __restrict__ bb,
                                float* __restrict__ out) {
    int idx = blockIdx.x*256 + threadIdx.x;
    if (idx >= R_*NL_) return;
    int r = idx / NL_, n = idx - r*NL_;
    float s = bb[n];
#pragma unroll
    for (int kc = 0; kc < S_; ++kc) s += (float)part[((size_t)kc*PR2_ + r)*112 + n];
    out[idx] = s;
}

extern "C" void kernel_launch(void* const* d_in, const int* in_sizes, int n_in,
                              void* d_out, int out_size, void* d_ws, size_t ws_size,
                              hipStream_t stream) {
    const float* seq   = (const float*)d_in[0];
    const float* att   = (const float*)d_in[1];
    const float* mmask = (const float*)d_in[2];
    const float* Wh    = (const float*)d_in[3];
    const float* bh    = (const float*)d_in[4];
    const float* Wt    = (const float*)d_in[5];
    const float* bt    = (const float*)d_in[6];
    const float* Wb    = (const float*)d_in[7];
    const float* bb    = (const float*)d_in[8];
    const int*   midx  = (const int*)d_in[9];
    const int*   hts   = (const int*)d_in[10];
    float* out = (float*)d_out;

    char* base = (char*)d_ws;
    _Float16* WbP  = (_Float16*)base;  base += (size_t)KT_*NTIL_*64*8 * 2;      // 11.0 MB
    _Float16* WhP  = (_Float16*)base;  base += (size_t)48*48*64*8 * 2;          //  2.4 MB
    _Float16* WtP  = (_Float16*)base;  base += (size_t)48*48*64*8 * 2;          //  2.4 MB
    _Float16* seqP = (_Float16*)base;  base += (size_t)B_*32*48*64*8 * 2;       //  6.3 MB
    _Float16* ee   = (_Float16*)base;  base += (size_t)B_*E_*H_ * 2;            //  0.15 MB
    _Float16* ea   = (_Float16*)base;  base += (size_t)B_*E_*NH_*L_ * 2;        //  2.4 MB
    _Float16* ht   = (_Float16*)base;  base += (size_t)R_*L_ * 2;               //  4.5 MB
    _Float16* rs   = (_Float16*)base;  base += (size_t)R_*H_ * 2;               //  3.4 MB
    _Float16* zh   = (_Float16*)base;  base += (size_t)R_*H_ * 2;               //  3.4 MB
    _Float16* zt   = (_Float16*)base;  base += (size_t)R_*H_ * 2;               //  3.4 MB
    _Float16* part = (_Float16*)base;                                           // 24.8 MB

    k_pack<<<dim3(PKB_ATT + PKB_WB2 + PKB_W2 + PKB_SEQ + PKB_EMB), dim3(256), 0, stream>>>(
        att, Wb, Wh, Wt, seq, midx, mmask, ea, WbP, WhP, WtP, seqP, ee);

    k_ht_att<<<dim3(R_), dim3(128), 0, stream>>>(ea, hts, ht);

    k_rs_mfma<<<dim3(240), dim3(256), 0, stream>>>(ht, seqP, rs);

    k_z_mfma<<<dim3(432), dim3(256), 0, stream>>>(ee, rs, WhP, WtP, bh, bt, hts, zh, zt);

    k_logits_mfma  <<<dim3(432), dim3(256), 0, stream>>>(zh, zt, WbP, part);
    k_logits_reduce<<<dim3((R_*NL_ + 255)/256), dim3(256), 0, stream>>>(part, bb, out);
}